// Round 1
// baseline (1057.444 us; speedup 1.0000x reference)
//
#include <hip/hip_runtime.h>
#include <hip/hip_bf16.h>
#include <math.h>

// Paged GQA decode attention, fp32.
// B=32 seqs, H=32 q-heads, KH=8 kv-heads (rep=4), D=128, BS=256 tok/block,
// MB=16 blocks/seq (max ctx 4096), NB=512 cache blocks.
//
// Key trick: the reference scatters the new k/v token at slot_mapping[b],
// which is exactly logical position ctx-1 of sequence b (block tables are
// disjoint across sequences). We never write the cache; instead the attention
// loop substitutes k/v from d_in when processing token ctx-1.
//
// Kernel 1 (flash-decode): one 256-thread WG per (chunk, kv-head, seq).
//   wave w handles tokens [w*64, w*64+64) of the chunk; lane l owns dims
//   {2l, 2l+1}. Per token: coalesced float2 K/V load, 64-lane shfl_xor
//   butterfly for the 4 rep-head dots, online softmax into registers.
//   Waves merge via LDS; partial (m,l,acc) per (b,g,chunk) goes to d_ws.
// Kernel 2: merge <=16 chunk partials per (b,g), normalize, write out.

#define BDIM 32
#define HDIM 32
#define KHDIM 8
#define DDIM 128
#define BSZ 256
#define MBLK 16
#define REP 4
#define ATT_SCALE 0.08838834764831845f

__global__ __launch_bounds__(256, 4)
void attn_chunk_kernel(const float* __restrict__ q,
                       const float* __restrict__ knew,
                       const float* __restrict__ vnew,
                       const float* __restrict__ kc,
                       const float* __restrict__ vc,
                       const int* __restrict__ bt,
                       const int* __restrict__ ctx_lens,
                       const int* __restrict__ slot_map,
                       float* __restrict__ ws_acc,
                       float* __restrict__ ws_ml)
{
    const int c = blockIdx.x;   // chunk (cache block index within seq)
    const int g = blockIdx.y;   // kv head
    const int b = blockIdx.z;   // sequence
    const int ctx = ctx_lens[b];
    const int start = c * BSZ;
    if (start >= ctx) return;                 // chunk beyond context
    const int len = min(BSZ, ctx - start);    // tokens in this chunk

    const int tid = threadIdx.x;
    const int w = tid >> 6;     // wave 0..3
    const int l = tid & 63;     // lane 0..63
    const int d0 = 2 * l;       // dims owned by this lane

    const int blk = bt[b * MBLK + c];
    // element (s,d) of this (blk,g): ((blk*BSZ+s)*KHDIM + g)*DDIM + d
    const float* kbase = kc + ((size_t)blk * BSZ * KHDIM + (size_t)g) * DDIM;
    const float* vbase = vc + ((size_t)blk * BSZ * KHDIM + (size_t)g) * DDIM;

    // q fragments for the 4 rep heads at dims d0,d0+1 (held in registers)
    float q0[REP], q1[REP];
#pragma unroll
    for (int r = 0; r < REP; ++r) {
        const float2 qq = *(const float2*)(q + (size_t)b * (HDIM * DDIM)
                                             + (size_t)(g * REP + r) * DDIM + d0);
        q0[r] = qq.x; q1[r] = qq.y;
    }

    const int slot = slot_map[b];
    const int last_local = (ctx - 1) - start;  // new token's position in chunk (may be outside)
    const float* knew_p = knew + ((size_t)b * KHDIM + g) * DDIM + d0;
    const float* vnew_p = vnew + ((size_t)b * KHDIM + g) * DDIM + d0;

    float m[REP], lsum[REP], acc0[REP], acc1[REP];
#pragma unroll
    for (int r = 0; r < REP; ++r) { m[r] = -INFINITY; lsum[r] = 0.f; acc0[r] = 0.f; acc1[r] = 0.f; }

    const int s_begin = w * 64;
    const int s_end = min(s_begin + 64, len);
    for (int s = s_begin; s < s_end; ++s) {
        float2 kk = *(const float2*)(kbase + (size_t)s * (KHDIM * DDIM) + d0);
        float2 vv = *(const float2*)(vbase + (size_t)s * (KHDIM * DDIM) + d0);
        if (s == last_local && slot >= 0) {    // wave-uniform branch
            kk = *(const float2*)knew_p;
            vv = *(const float2*)vnew_p;
        }
        float sc[REP];
#pragma unroll
        for (int r = 0; r < REP; ++r)
            sc[r] = q0[r] * kk.x + q1[r] * kk.y;
        // 64-lane butterfly sum -> every lane has the full dot products
#pragma unroll
        for (int off = 32; off > 0; off >>= 1) {
#pragma unroll
            for (int r = 0; r < REP; ++r)
                sc[r] += __shfl_xor(sc[r], off, 64);
        }
#pragma unroll
        for (int r = 0; r < REP; ++r) {
            const float sr = sc[r] * ATT_SCALE;
            const float mn = fmaxf(m[r], sr);
            const float alpha = __expf(m[r] - mn);   // exp(-inf)=0 on first token
            const float p = __expf(sr - mn);
            m[r] = mn;
            lsum[r] = lsum[r] * alpha + p;
            acc0[r] = acc0[r] * alpha + p * vv.x;
            acc1[r] = acc1[r] * alpha + p * vv.y;
        }
    }

    // ---- merge the 4 waves via LDS ----
    __shared__ float lds_ml[4][REP][2];
    __shared__ float lds_acc[4][REP][DDIM];   // 8 KB
    __shared__ float lds_coef[4][REP];
    __shared__ float lds_mf[REP], lds_lf[REP];

    if (l == 0) {
#pragma unroll
        for (int r = 0; r < REP; ++r) { lds_ml[w][r][0] = m[r]; lds_ml[w][r][1] = lsum[r]; }
    }
#pragma unroll
    for (int r = 0; r < REP; ++r) {
        *(float2*)&lds_acc[w][r][d0] = make_float2(acc0[r], acc1[r]);
    }
    __syncthreads();

    if (tid < REP) {
        const int r = tid;
        float mf = -INFINITY;
#pragma unroll
        for (int w2 = 0; w2 < 4; ++w2) mf = fmaxf(mf, lds_ml[w2][r][0]);
        float lf = 0.f;
#pragma unroll
        for (int w2 = 0; w2 < 4; ++w2) {
            const float cf = __expf(lds_ml[w2][r][0] - mf);  // idle wave: exp(-inf)=0
            lds_coef[w2][r] = cf;
            lf += cf * lds_ml[w2][r][1];
        }
        lds_mf[r] = mf;
        lds_lf[r] = lf;
    }
    __syncthreads();

    float* wacc = ws_acc + (((size_t)b * KHDIM + g) * MBLK + c) * (REP * DDIM);
#pragma unroll
    for (int e = tid; e < REP * DDIM; e += 256) {
        const int r = e >> 7;
        const int d = e & (DDIM - 1);
        float sum = 0.f;
#pragma unroll
        for (int w2 = 0; w2 < 4; ++w2) sum += lds_coef[w2][r] * lds_acc[w2][r][d];
        wacc[e] = sum;
    }
    if (tid < REP) {
        float* wml = ws_ml + (((size_t)b * KHDIM + g) * MBLK + c) * (REP * 2);
        wml[tid * 2 + 0] = lds_mf[tid];
        wml[tid * 2 + 1] = lds_lf[tid];
    }
}

__global__ __launch_bounds__(256)
void attn_reduce_kernel(const float* __restrict__ ws_acc,
                        const float* __restrict__ ws_ml,
                        const int* __restrict__ ctx_lens,
                        float* __restrict__ out)
{
    const int g = blockIdx.x;   // kv head
    const int b = blockIdx.y;   // sequence
    const int ctx = ctx_lens[b];
    const int nc = (ctx + BSZ - 1) / BSZ;     // number of valid chunks
    const int tid = threadIdx.x;

    __shared__ float coef[MBLK][REP];
    __shared__ float linv[REP];

    const float* wml = ws_ml + (((size_t)b * KHDIM + g) * MBLK) * (REP * 2);
    if (tid < REP) {
        const int r = tid;
        float mf = -INFINITY;
        for (int c = 0; c < nc; ++c) mf = fmaxf(mf, wml[c * REP * 2 + r * 2]);
        float lf = 0.f;
        for (int c = 0; c < nc; ++c) {
            const float cf = __expf(wml[c * REP * 2 + r * 2] - mf);
            coef[c][r] = cf;
            lf += cf * wml[c * REP * 2 + r * 2 + 1];
        }
        linv[r] = 1.0f / lf;
    }
    __syncthreads();

    const float* wacc = ws_acc + (((size_t)b * KHDIM + g) * MBLK) * (REP * DDIM);
    for (int e = tid; e < REP * DDIM; e += 256) {
        const int r = e >> 7;
        float sum = 0.f;
        for (int c = 0; c < nc; ++c) sum += coef[c][r] * wacc[c * (REP * DDIM) + e];
        out[(size_t)b * (HDIM * DDIM) + (size_t)g * (REP * DDIM) + e] = sum * linv[r];
    }
}

extern "C" void kernel_launch(void* const* d_in, const int* in_sizes, int n_in,
                              void* d_out, int out_size, void* d_ws, size_t ws_size,
                              hipStream_t stream) {
    const float* q    = (const float*)d_in[0];
    const float* knew = (const float*)d_in[1];
    const float* vnew = (const float*)d_in[2];
    const float* kc   = (const float*)d_in[3];
    const float* vc   = (const float*)d_in[4];
    const int* bt     = (const int*)d_in[5];
    const int* ctx    = (const int*)d_in[6];
    const int* slot   = (const int*)d_in[7];
    float* out = (float*)d_out;

    // workspace layout: acc [32][8][16][4*128] floats (8 MB), then ml [32][8][16][4][2]
    float* ws_acc = (float*)d_ws;
    float* ws_ml  = ws_acc + (size_t)BDIM * KHDIM * MBLK * REP * DDIM;

    dim3 grid1(MBLK, KHDIM, BDIM);   // (16, 8, 32)
    attn_chunk_kernel<<<grid1, 256, 0, stream>>>(q, knew, vnew, kc, vc, bt, ctx, slot,
                                                 ws_acc, ws_ml);
    dim3 grid2(KHDIM, BDIM);         // (8, 32)
    attn_reduce_kernel<<<grid2, 256, 0, stream>>>(ws_acc, ws_ml, ctx, out);
}

// Round 2
// 976.189 us; speedup vs baseline: 1.0832x; 1.0832x over previous
//
#include <hip/hip_runtime.h>
#include <hip/hip_bf16.h>
#include <math.h>

// Paged GQA decode attention, fp32.
// B=32 seqs, H=32 q-heads, KH=8 kv-heads (rep=4), D=128, BS=256 tok/block,
// MB=16 blocks/seq (max ctx 4096), NB=512 cache blocks.
//
// The reference's scatter lands the new k/v token exactly at logical position
// ctx-1 of its own sequence (block tables are disjoint), so we never write the
// cache; the attention loop substitutes k/v from d_in at token ctx-1.
//
// Kernel 1 (flash-decode, thread-group layout): one 256-thread WG per
// (chunk, kv-head, seq). Wave w owns tokens [w*64, w*64+64). Within a wave,
// 16-lane groups each own one token per iteration (4 tokens/wave/iter);
// lane c16 owns dims 8*c16..8*c16+7 via two float4 loads. Dot reduction is a
// 4-step within-16 xor butterfly (one ds_swizzle per step, all 4 groups at
// once). Each group keeps independent online-softmax state; groups merge via
// xor16/xor32 shuffles at wave end (-inf-safe coefficients), waves merge via
// LDS; per-(b,g,chunk) partial (m,l,acc) goes to d_ws.
// Kernel 2: merge <=16 chunk partials per (b,g), normalize, write out.

#define BDIM 32
#define HDIM 32
#define KHDIM 8
#define DDIM 128
#define BSZ 256
#define MBLK 16
#define REP 4
#define ATT_SCALE 0.08838834764831845f

__global__ __launch_bounds__(256, 4)
void attn_chunk_kernel(const float* __restrict__ q,
                       const float* __restrict__ knew,
                       const float* __restrict__ vnew,
                       const float* __restrict__ kc,
                       const float* __restrict__ vc,
                       const int* __restrict__ bt,
                       const int* __restrict__ ctx_lens,
                       const int* __restrict__ slot_map,
                       float* __restrict__ ws_acc,
                       float* __restrict__ ws_ml)
{
    const int c = blockIdx.x;   // chunk (cache block index within seq)
    const int g = blockIdx.y;   // kv head
    const int b = blockIdx.z;   // sequence
    const int ctx = ctx_lens[b];
    const int start = c * BSZ;
    if (start >= ctx) return;                 // chunk beyond context
    const int len = min(BSZ, ctx - start);    // tokens in this chunk

    const int tid = threadIdx.x;
    const int w = tid >> 6;     // wave 0..3
    const int l = tid & 63;     // lane 0..63
    const int grp = l >> 4;     // token subgroup 0..3 within wave
    const int c16 = l & 15;     // lane within group
    const int d0 = 8 * c16;     // dims owned: d0..d0+7

    const int blk = bt[b * MBLK + c];
    // element (s,d) of this (blk,g): ((blk*BSZ+s)*KHDIM + g)*DDIM + d
    const float* kbase = kc + ((size_t)blk * BSZ * KHDIM + (size_t)g) * DDIM;
    const float* vbase = vc + ((size_t)blk * BSZ * KHDIM + (size_t)g) * DDIM;

    // q fragments for the 4 rep heads at dims d0..d0+7
    float4 qa[REP], qb[REP];
#pragma unroll
    for (int r = 0; r < REP; ++r) {
        const float* qp = q + (size_t)b * (HDIM * DDIM)
                            + (size_t)(g * REP + r) * DDIM + d0;
        qa[r] = *(const float4*)qp;
        qb[r] = *(const float4*)(qp + 4);
    }

    const int slot = slot_map[b];
    const int last_local = (ctx - 1) - start;  // new token's chunk-local pos (may be outside)
    const float* knew_p = knew + ((size_t)b * KHDIM + g) * DDIM + d0;
    const float* vnew_p = vnew + ((size_t)b * KHDIM + g) * DDIM + d0;

    float m[REP], lsum[REP];
    float4 acca[REP], accb[REP];
#pragma unroll
    for (int r = 0; r < REP; ++r) {
        m[r] = -INFINITY; lsum[r] = 0.f;
        acca[r] = make_float4(0.f, 0.f, 0.f, 0.f);
        accb[r] = make_float4(0.f, 0.f, 0.f, 0.f);
    }

    const int wend = min(len, w * 64 + 64);
    for (int t = w * 64 + grp; t < wend; t += 4) {   // group-uniform trip
        const float* kp = kbase + (size_t)t * (KHDIM * DDIM) + d0;
        const float* vp = vbase + (size_t)t * (KHDIM * DDIM) + d0;
        float4 k0 = *(const float4*)kp;
        float4 k1 = *(const float4*)(kp + 4);
        float4 v0 = *(const float4*)vp;
        float4 v1 = *(const float4*)(vp + 4);
        if (t == last_local && slot >= 0) {          // group-uniform branch
            k0 = *(const float4*)knew_p; k1 = *(const float4*)(knew_p + 4);
            v0 = *(const float4*)vnew_p; v1 = *(const float4*)(vnew_p + 4);
        }
        float sc[REP];
#pragma unroll
        for (int r = 0; r < REP; ++r) {
            sc[r] = qa[r].x * k0.x + qa[r].y * k0.y + qa[r].z * k0.z + qa[r].w * k0.w
                  + qb[r].x * k1.x + qb[r].y * k1.y + qb[r].z * k1.z + qb[r].w * k1.w;
        }
        // 4-step butterfly within each 16-lane group (single ds_swizzle/step)
#pragma unroll
        for (int off = 8; off >= 1; off >>= 1) {
#pragma unroll
            for (int r = 0; r < REP; ++r)
                sc[r] += __shfl_xor(sc[r], off, 64);
        }
#pragma unroll
        for (int r = 0; r < REP; ++r) {
            const float sr = sc[r] * ATT_SCALE;
            const float mn = fmaxf(m[r], sr);
            const float alpha = __expf(m[r] - mn);   // m=-inf first token -> 0
            const float p = __expf(sr - mn);
            m[r] = mn;
            lsum[r] = lsum[r] * alpha + p;
            acca[r].x = acca[r].x * alpha + p * v0.x;
            acca[r].y = acca[r].y * alpha + p * v0.y;
            acca[r].z = acca[r].z * alpha + p * v0.z;
            acca[r].w = acca[r].w * alpha + p * v0.w;
            accb[r].x = accb[r].x * alpha + p * v1.x;
            accb[r].y = accb[r].y * alpha + p * v1.y;
            accb[r].z = accb[r].z * alpha + p * v1.z;
            accb[r].w = accb[r].w * alpha + p * v1.w;
        }
    }

    // ---- intra-wave merge of the 4 group states: xor16 then xor32 ----
    // -inf-safe coefficients: if both states empty (m==mo==-inf), coefs are 1
    // and accs are 0 (avoids exp(-inf - -inf) = NaN).
#pragma unroll
    for (int off = 16; off <= 32; off <<= 1) {
#pragma unroll
        for (int r = 0; r < REP; ++r) {
            const float mo = __shfl_xor(m[r], off, 64);
            const float lo = __shfl_xor(lsum[r], off, 64);
            const float mn = fmaxf(m[r], mo);
            const float as = (m[r] == mn) ? 1.f : __expf(m[r] - mn);
            const float ao = (mo   == mn) ? 1.f : __expf(mo   - mn);
            float4 oa, ob;
            oa.x = __shfl_xor(acca[r].x, off, 64);
            oa.y = __shfl_xor(acca[r].y, off, 64);
            oa.z = __shfl_xor(acca[r].z, off, 64);
            oa.w = __shfl_xor(acca[r].w, off, 64);
            ob.x = __shfl_xor(accb[r].x, off, 64);
            ob.y = __shfl_xor(accb[r].y, off, 64);
            ob.z = __shfl_xor(accb[r].z, off, 64);
            ob.w = __shfl_xor(accb[r].w, off, 64);
            acca[r].x = acca[r].x * as + oa.x * ao;
            acca[r].y = acca[r].y * as + oa.y * ao;
            acca[r].z = acca[r].z * as + oa.z * ao;
            acca[r].w = acca[r].w * as + oa.w * ao;
            accb[r].x = accb[r].x * as + ob.x * ao;
            accb[r].y = accb[r].y * as + ob.y * ao;
            accb[r].z = accb[r].z * as + ob.z * ao;
            accb[r].w = accb[r].w * as + ob.w * ao;
            lsum[r] = lsum[r] * as + lo * ao;
            m[r] = mn;
        }
    }
    // now every lane holds the wave-merged (m,l); lane c16 holds acc dims d0..d0+7

    // ---- merge the 4 waves via LDS ----
    __shared__ float lds_ml[4][REP][2];
    __shared__ float lds_acc[4][REP][DDIM];   // 8 KB
    __shared__ float lds_coef[4][REP];
    __shared__ float lds_mf[REP], lds_lf[REP];

    if (l == 0) {
#pragma unroll
        for (int r = 0; r < REP; ++r) { lds_ml[w][r][0] = m[r]; lds_ml[w][r][1] = lsum[r]; }
    }
    if (grp == 0) {
#pragma unroll
        for (int r = 0; r < REP; ++r) {
            *(float4*)&lds_acc[w][r][d0]     = acca[r];
            *(float4*)&lds_acc[w][r][d0 + 4] = accb[r];
        }
    }
    __syncthreads();

    if (tid < REP) {
        const int r = tid;
        float mf = -INFINITY;
#pragma unroll
        for (int w2 = 0; w2 < 4; ++w2) mf = fmaxf(mf, lds_ml[w2][r][0]);
        float lf = 0.f;
#pragma unroll
        for (int w2 = 0; w2 < 4; ++w2) {
            const float cf = __expf(lds_ml[w2][r][0] - mf);  // empty wave: exp(-inf)=0
            lds_coef[w2][r] = cf;
            lf += cf * lds_ml[w2][r][1];
        }
        lds_mf[r] = mf;
        lds_lf[r] = lf;
    }
    __syncthreads();

    float* wacc = ws_acc + (((size_t)b * KHDIM + g) * MBLK + c) * (REP * DDIM);
#pragma unroll
    for (int e = tid; e < REP * DDIM; e += 256) {
        const int r = e >> 7;
        const int d = e & (DDIM - 1);
        float sum = 0.f;
#pragma unroll
        for (int w2 = 0; w2 < 4; ++w2) sum += lds_coef[w2][r] * lds_acc[w2][r][d];
        wacc[e] = sum;
    }
    if (tid < REP) {
        float* wml = ws_ml + (((size_t)b * KHDIM + g) * MBLK + c) * (REP * 2);
        wml[tid * 2 + 0] = lds_mf[tid];
        wml[tid * 2 + 1] = lds_lf[tid];
    }
}

__global__ __launch_bounds__(256)
void attn_reduce_kernel(const float* __restrict__ ws_acc,
                        const float* __restrict__ ws_ml,
                        const int* __restrict__ ctx_lens,
                        float* __restrict__ out)
{
    const int g = blockIdx.x;   // kv head
    const int b = blockIdx.y;   // sequence
    const int ctx = ctx_lens[b];
    const int nc = (ctx + BSZ - 1) / BSZ;     // number of valid chunks
    const int tid = threadIdx.x;

    __shared__ float coef[MBLK][REP];
    __shared__ float linv[REP];

    const float* wml = ws_ml + (((size_t)b * KHDIM + g) * MBLK) * (REP * 2);
    if (tid < REP) {
        const int r = tid;
        float mf = -INFINITY;
        for (int c = 0; c < nc; ++c) mf = fmaxf(mf, wml[c * REP * 2 + r * 2]);
        float lf = 0.f;
        for (int c = 0; c < nc; ++c) {
            const float cf = __expf(wml[c * REP * 2 + r * 2] - mf);
            coef[c][r] = cf;
            lf += cf * wml[c * REP * 2 + r * 2 + 1];
        }
        linv[r] = 1.0f / lf;
    }
    __syncthreads();

    const float* wacc = ws_acc + (((size_t)b * KHDIM + g) * MBLK) * (REP * DDIM);
    for (int e = tid; e < REP * DDIM; e += 256) {
        const int r = e >> 7;
        float sum = 0.f;
        for (int c = 0; c < nc; ++c) sum += coef[c][r] * wacc[c * (REP * DDIM) + e];
        out[(size_t)b * (HDIM * DDIM) + (size_t)g * (REP * DDIM) + e] = sum * linv[r];
    }
}

extern "C" void kernel_launch(void* const* d_in, const int* in_sizes, int n_in,
                              void* d_out, int out_size, void* d_ws, size_t ws_size,
                              hipStream_t stream) {
    const float* q    = (const float*)d_in[0];
    const float* knew = (const float*)d_in[1];
    const float* vnew = (const float*)d_in[2];
    const float* kc   = (const float*)d_in[3];
    const float* vc   = (const float*)d_in[4];
    const int* bt     = (const int*)d_in[5];
    const int* ctx    = (const int*)d_in[6];
    const int* slot   = (const int*)d_in[7];
    float* out = (float*)d_out;

    // workspace layout: acc [32][8][16][4*128] floats (8 MB), then ml [32][8][16][4][2]
    float* ws_acc = (float*)d_ws;
    float* ws_ml  = ws_acc + (size_t)BDIM * KHDIM * MBLK * REP * DDIM;

    dim3 grid1(MBLK, KHDIM, BDIM);   // (16, 8, 32)
    attn_chunk_kernel<<<grid1, 256, 0, stream>>>(q, knew, vnew, kc, vc, bt, ctx, slot,
                                                 ws_acc, ws_ml);
    dim3 grid2(KHDIM, BDIM);         // (8, 32)
    attn_reduce_kernel<<<grid2, 256, 0, stream>>>(ws_acc, ws_ml, ctx, out);
}